// Round 8
// baseline (68.944 us; speedup 1.0000x reference)
//
#include <hip/hip_runtime.h>

#define BB 32
#define FF 8
#define NN 131072
#define CC 16

#define CHUNKS 64
#define POINTS (NN / CHUNKS)   // 2048
#define NBLK   (CHUNKS * BB)   // 2048

constexpr float DELTA_VAR  = 0.5f;
constexpr float DELTA_DIST = 1.5f;
constexpr float ALPHA = 1.0f, BETA = 1.0f, GAMMA = 0.001f;

// ws float layout. Partials are written (K1) before read (K2). The small
// accumulator block [WS_VARB, WS_CNTI] is zero-initialized by K1 (plain
// stores; dispatch boundary orders them before K2's atomics).
#define PSLOT    160                       // 144 used, padded
#define WS_PART  0                         // NBLK*PSLOT
#define NPART    (NBLK * PSLOT)            // 327680
#define WS_VARB  NPART                     // 32: per-batch var sums (atomic)
#define WS_DRG   (NPART + 32)              // 32: per-batch dist+reg (atomic)
#define WS_CNTI  (NPART + 64)              // 1 int: finisher counter

// ---------------- Pass 1: per-chunk sums + counts --------------------------
// 4 feature-pair groups x 64 lanes; private float2 rows (stride 34 floats).
__global__ __launch_bounds__(256) void k_sums(const float* __restrict__ x,
                                              const int* __restrict__ tgt,
                                              float* __restrict__ ws,
                                              int* __restrict__ wsi) {
    __shared__ float priv[256 * 34];   // 34 KB private float2 rows
    __shared__ float cpriv[64 * 17];   // 4.3 KB counts (fp==0 group)
    const int tid = threadIdx.x;
    const int b  = blockIdx.y;
    const int ch = blockIdx.x;

    // zero the cross-kernel accumulators (once per batch / once per grid)
    if (ch == 0 && tid == 0) { ws[WS_VARB + b] = 0.f; ws[WS_DRG + b] = 0.f; }
    if (ch == 0 && b == 0 && tid == 1) wsi[WS_CNTI] = 0;

#pragma unroll
    for (int i = 0; i < 34; ++i) priv[tid * 34 + i] = 0.f;
    if (tid < 64) {
#pragma unroll
        for (int i = 0; i < 16; ++i) cpriv[tid * 17 + i] = 0.f;
    }
    __syncthreads();

    const int fp = tid >> 6;          // feature pair 0..3
    const int g  = tid & 63;          // lane
    const int n0 = ch * POINTS;
    const float* __restrict__ xf0 = x + (size_t)b * FF * NN + (size_t)(2 * fp) * NN;
    const float* __restrict__ xf1 = xf0 + NN;
    const int*   __restrict__ tb  = tgt + (size_t)b * NN;
    const int base  = tid * 34;
    const int cbase = g * 17;

#pragma unroll 2
    for (int k = 0; k < POINTS / 128; ++k) {
        const int n = n0 + k * 128 + g * 2;
        const int2   t2 = *reinterpret_cast<const int2*>(tb + n);
        const float2 v0 = *reinterpret_cast<const float2*>(xf0 + n);
        const float2 v1 = *reinterpret_cast<const float2*>(xf1 + n);
        {
            float2* p = reinterpret_cast<float2*>(&priv[base + 2 * t2.x]);
            float2 cur = *p; cur.x += v0.x; cur.y += v1.x; *p = cur;
        }
        {
            float2* p = reinterpret_cast<float2*>(&priv[base + 2 * t2.y]);
            float2 cur = *p; cur.x += v0.y; cur.y += v1.y; *p = cur;
        }
        if (fp == 0) {
            cpriv[cbase + t2.x] += 1.f;
            cpriv[cbase + t2.y] += 1.f;
        }
    }
    __syncthreads();

    // block reduce -> per-block partial slots (plain stores, no atomics)
    float* const part = &ws[WS_PART + (size_t)(b * CHUNKS + ch) * PSLOT];
    if (tid < 128) {
        const int f = tid >> 4, c = tid & 15;     // slot = f*16 + c
        const int pair = f >> 1, comp = f & 1;
        float s = 0.f;
#pragma unroll
        for (int gg = 0; gg < 64; ++gg)
            s += priv[(pair * 64 + gg) * 34 + 2 * c + comp];
        part[tid] = s;
    } else if (tid < 144) {
        const int rc = tid - 128;
        float s = 0.f;
#pragma unroll
        for (int gg = 0; gg < 64; ++gg) s += cpriv[gg * 17 + rc];
        part[tid] = s;
    }
}

// ---------------- Pass 2: variance + dist/reg + finisher --------------------
__global__ __launch_bounds__(256) void k_var(const float* __restrict__ x,
                                             const int* __restrict__ tgt,
                                             float* __restrict__ ws,
                                             int* __restrict__ wsi,
                                             float* __restrict__ out) {
    __shared__ float sred[144];
    __shared__ float smf[CC * 12];     // float4-pair rows at stride 3 float4s
    __shared__ float sinv[CC];
    __shared__ float wsum[4];
    __shared__ float sdist[CC];
    __shared__ int   sst[CC];
    __shared__ int   lastflag;

    const int tid = threadIdx.x;
    const int b   = blockIdx.y;
    const int ch  = blockIdx.x;

    // ---- prologue: derive means/inv from the 64 chunk partials ----
    if (tid < 144) {
        const float* p = &ws[WS_PART + (size_t)b * CHUNKS * PSLOT + tid];
        float s = 0.f;
#pragma unroll 8
        for (int c2 = 0; c2 < CHUNKS; ++c2) s += p[(size_t)c2 * PSLOT];
        sred[tid] = s;
    }
    if (ch == 0 && tid >= 144 && tid < 160) sst[tid - 144] = tgt[(size_t)b * NN + (tid - 144)];
    __syncthreads();
    if (tid < CC) {
        const float cnt = sred[128 + tid];
        sinv[tid] = cnt > 0.f ? 1.f / cnt : 0.f;
    }
    __syncthreads();
    if (tid < 128) {
        const int f = tid >> 4, c = tid & 15;
        smf[c * 12 + f] = sred[tid] * sinv[c];
    }
    __syncthreads();

    // ---- ch==0 blocks: dist + reg terms (threads 0..15, overlaps main loop)
    if (ch == 0 && tid < CC) {
        const int c = tid;
        float l1 = 0.f;
#pragma unroll
        for (int f = 0; f < FF; ++f) l1 += fabsf(smf[c * 12 + f]);
        const int ti = sst[c];
        float mi[FF];
#pragma unroll
        for (int f = 0; f < FF; ++f) mi[f] = smf[ti * 12 + f];
        float dsum = 0.f;
        for (int j = 0; j < CC; ++j) {
            const int tj = sst[j];
            float d = 0.f;
#pragma unroll
            for (int f = 0; f < FF; ++f) d += fabsf(mi[f] - smf[tj * 12 + f]);
            if (j != c) {
                const float h = 2.f * DELTA_DIST - d;
                if (h > 0.f) dsum += h * h;
            }
        }
        sdist[c] = (GAMMA / (float)(CC * BB)) * l1
                 + (BETA / (float)(CC * (CC - 1) * BB)) * dsum;
    }

    // ---- main loop: variance term over own chunk ----
    const float4* sm4 = reinterpret_cast<const float4*>(smf);
    const int n0 = ch * POINTS;
    const float* __restrict__ xb = x + (size_t)b * FF * NN;
    const int*   __restrict__ tb = tgt + (size_t)b * NN;

    float acc = 0.f;
#pragma unroll
    for (int it = 0; it < 2; ++it) {
        const int n = n0 + tid * 4 + it * 1024;
        const int4 t4 = *reinterpret_cast<const int4*>(tb + n);
        const float4 A0 = sm4[3 * t4.x], B0 = sm4[3 * t4.x + 1];
        const float4 A1 = sm4[3 * t4.y], B1 = sm4[3 * t4.y + 1];
        const float4 A2 = sm4[3 * t4.z], B2 = sm4[3 * t4.z + 1];
        const float4 A3 = sm4[3 * t4.w], B3 = sm4[3 * t4.w + 1];
        float s0, s1, s2, s3;
        {
            const float4 v = *reinterpret_cast<const float4*>(xb + 0 * NN + n);
            s0 = fabsf(v.x - A0.x); s1 = fabsf(v.y - A1.x);
            s2 = fabsf(v.z - A2.x); s3 = fabsf(v.w - A3.x);
        }
        {
            const float4 v = *reinterpret_cast<const float4*>(xb + 1 * NN + n);
            s0 += fabsf(v.x - A0.y); s1 += fabsf(v.y - A1.y);
            s2 += fabsf(v.z - A2.y); s3 += fabsf(v.w - A3.y);
        }
        {
            const float4 v = *reinterpret_cast<const float4*>(xb + 2 * NN + n);
            s0 += fabsf(v.x - A0.z); s1 += fabsf(v.y - A1.z);
            s2 += fabsf(v.z - A2.z); s3 += fabsf(v.w - A3.z);
        }
        {
            const float4 v = *reinterpret_cast<const float4*>(xb + 3 * NN + n);
            s0 += fabsf(v.x - A0.w); s1 += fabsf(v.y - A1.w);
            s2 += fabsf(v.z - A2.w); s3 += fabsf(v.w - A3.w);
        }
        {
            const float4 v = *reinterpret_cast<const float4*>(xb + 4 * NN + n);
            s0 += fabsf(v.x - B0.x); s1 += fabsf(v.y - B1.x);
            s2 += fabsf(v.z - B2.x); s3 += fabsf(v.w - B3.x);
        }
        {
            const float4 v = *reinterpret_cast<const float4*>(xb + 5 * NN + n);
            s0 += fabsf(v.x - B0.y); s1 += fabsf(v.y - B1.y);
            s2 += fabsf(v.z - B2.y); s3 += fabsf(v.w - B3.y);
        }
        {
            const float4 v = *reinterpret_cast<const float4*>(xb + 6 * NN + n);
            s0 += fabsf(v.x - B0.z); s1 += fabsf(v.y - B1.z);
            s2 += fabsf(v.z - B2.z); s3 += fabsf(v.w - B3.z);
        }
        {
            const float4 v = *reinterpret_cast<const float4*>(xb + 7 * NN + n);
            s0 += fabsf(v.x - B0.w); s1 += fabsf(v.y - B1.w);
            s2 += fabsf(v.z - B2.w); s3 += fabsf(v.w - B3.w);
        }
        float h;
        h = fmaxf(s0 - DELTA_VAR, 0.f); acc += h * h * sinv[t4.x];
        h = fmaxf(s1 - DELTA_VAR, 0.f); acc += h * h * sinv[t4.y];
        h = fmaxf(s2 - DELTA_VAR, 0.f); acc += h * h * sinv[t4.z];
        h = fmaxf(s3 - DELTA_VAR, 0.f); acc += h * h * sinv[t4.w];
    }

#pragma unroll
    for (int off = 32; off > 0; off >>= 1) acc += __shfl_down(acc, off, 64);
    if ((tid & 63) == 0) wsum[tid >> 6] = acc;
    __syncthreads();

    // ---- fence-free finisher handshake (atomics only, waitcnt release) ----
    if (tid == 0) {
        atomicAdd(&ws[WS_VARB + b], wsum[0] + wsum[1] + wsum[2] + wsum[3]);
        if (ch == 0) {
            float drg = 0.f;
#pragma unroll
            for (int i = 0; i < CC; ++i) drg += sdist[i];
            atomicAdd(&ws[WS_DRG + b], drg);
        }
        asm volatile("s_waitcnt vmcnt(0)" ::: "memory");   // drain own atomics
        lastflag = (atomicAdd(&wsi[WS_CNTI], 1) == NBLK - 1);
    }
    __syncthreads();
    if (lastflag && tid < 64) {
        float val = 0.f;
        if (tid < BB) {
            const float v = atomicAdd(&ws[WS_VARB + tid], 0.f);  // coherent read
            const float d = atomicAdd(&ws[WS_DRG + tid], 0.f);
            val = (ALPHA / (float)BB) * v + d;
        }
#pragma unroll
        for (int off = 16; off > 0; off >>= 1) val += __shfl_down(val, off, 64);
        if (tid == 0) out[0] = val;
    }
}

extern "C" void kernel_launch(void* const* d_in, const int* in_sizes, int n_in,
                              void* d_out, int out_size, void* d_ws, size_t ws_size,
                              hipStream_t stream) {
    const float* x  = (const float*)d_in[0];
    const int* tgt  = (const int*)d_in[1];
    float* out = (float*)d_out;
    float* ws  = (float*)d_ws;
    int*   wsi = (int*)d_ws;

    dim3 grid(CHUNKS, BB);
    k_sums<<<grid, 256, 0, stream>>>(x, tgt, ws, wsi);
    k_var <<<grid, 256, 0, stream>>>(x, tgt, ws, wsi, out);
}

// Round 9
// 68.332 us; speedup vs baseline: 1.0090x; 1.0090x over previous
//
#include <hip/hip_runtime.h>

#define BB 32
#define FF 8
#define NN 131072
#define CC 16

#define CHUNKS 64
#define POINTS (NN / CHUNKS)   // 2048
#define NBLK   (CHUNKS * BB)   // 2048

constexpr float DELTA_VAR  = 0.5f;
constexpr float DELTA_DIST = 1.5f;
constexpr float ALPHA = 1.0f, BETA = 1.0f, GAMMA = 0.001f;

// ws float layout. Partials: written by K1, read by K2 (dispatch boundary
// orders them). Small accumulators zero-initialized by K1's ch==0 blocks.
#define PSLOT    160                       // 144 used, padded
#define WS_PART  0                         // NBLK*PSLOT
#define NPART    (NBLK * PSLOT)            // 327680
#define WS_VARB  NPART                     // 32: per-batch var sums (atomic)
#define WS_DRG   (NPART + 32)              // 32: per-batch dist+reg (atomic)
#define WS_CNTI  (NPART + 64)              // 1 int: finisher counter

// ---------------- Pass 1: per-chunk sums + counts (R6-proven) ---------------
__global__ __launch_bounds__(256) void k_sums(const float* __restrict__ x,
                                              const int* __restrict__ tgt,
                                              float* __restrict__ ws,
                                              int* __restrict__ wsi) {
    __shared__ float priv[256 * 17];   // 17.4 KB private rows, stride 17
    __shared__ float cpriv[32 * 17];   //  2.2 KB counts (f==0 group)
    const int tid = threadIdx.x;
    const int b  = blockIdx.y;
    const int ch = blockIdx.x;

    // zero cross-kernel accumulators (dispatch boundary orders before K2)
    if (ch == 0 && tid == 0) { ws[WS_VARB + b] = 0.f; ws[WS_DRG + b] = 0.f; }
    if (ch == 0 && b == 0 && tid == 1) wsi[WS_CNTI] = 0;

#pragma unroll
    for (int i = 0; i < 16; ++i) priv[tid * 17 + i] = 0.f;
    if (tid < 32) {
#pragma unroll
        for (int i = 0; i < 16; ++i) cpriv[tid * 17 + i] = 0.f;
    }
    __syncthreads();

    const int f  = tid >> 5;          // feature group 0..7
    const int g  = tid & 31;          // lane-in-group
    const int n0 = ch * POINTS;
    const float* __restrict__ xf = x + (size_t)b * FF * NN + (size_t)f * NN;
    const int*   __restrict__ tb = tgt + (size_t)b * NN;
    const int base  = tid * 17;
    const int cbase = g * 17;

#pragma unroll 2
    for (int k = 0; k < POINTS / 128; ++k) {
        const int n = n0 + k * 128 + g * 4;
        const int4   t4 = *reinterpret_cast<const int4*>(tb + n);
        const float4 v  = *reinterpret_cast<const float4*>(xf + n);
        priv[base + t4.x] += v.x;
        priv[base + t4.y] += v.y;
        priv[base + t4.z] += v.z;
        priv[base + t4.w] += v.w;
        if (f == 0) {
            cpriv[cbase + t4.x] += 1.f;
            cpriv[cbase + t4.y] += 1.f;
            cpriv[cbase + t4.z] += 1.f;
            cpriv[cbase + t4.w] += 1.f;
        }
    }
    __syncthreads();

    // block reduce -> per-block partial slots (plain stores, no atomics)
    float* const part = &ws[WS_PART + (size_t)(b * CHUNKS + ch) * PSLOT];
    if (tid < 128) {
        const int rf = tid >> 4, rc = tid & 15;   // slot = f*16 + c
        float s = 0.f;
#pragma unroll
        for (int gg = 0; gg < 32; ++gg) s += priv[(rf * 32 + gg) * 17 + rc];
        part[tid] = s;
    } else if (tid < 144) {
        const int rc = tid - 128;
        float s = 0.f;
#pragma unroll
        for (int gg = 0; gg < 32; ++gg) s += cpriv[gg * 17 + rc];
        part[tid] = s;
    }
}

// ---------------- Pass 2: variance + dist/reg + spin-finisher ---------------
__global__ __launch_bounds__(256) void k_var(const float* __restrict__ x,
                                             const int* __restrict__ tgt,
                                             float* __restrict__ ws,
                                             int* __restrict__ wsi,
                                             float* __restrict__ out) {
    __shared__ float sred[144];
    __shared__ float smf[CC * 12];     // float4-pair rows at stride 3 float4s
    __shared__ float sinv[CC];
    __shared__ float wsum[4];

    const int tid = threadIdx.x;
    const int b   = blockIdx.y;
    const int ch  = blockIdx.x;

    // ---- prologue: derive means/inv from the 64 chunk partials ----
    if (tid < 144) {
        const float* p = &ws[WS_PART + (size_t)b * CHUNKS * PSLOT + tid];
        float s = 0.f;
#pragma unroll 8
        for (int c2 = 0; c2 < CHUNKS; ++c2) s += p[(size_t)c2 * PSLOT];
        sred[tid] = s;
    }
    __syncthreads();
    if (tid < CC) {
        const float cnt = sred[128 + tid];
        sinv[tid] = cnt > 0.f ? 1.f / cnt : 0.f;
    }
    __syncthreads();
    if (tid < 128) {
        const int f = tid >> 4, c = tid & 15;
        smf[c * 12 + f] = sred[tid] * sinv[c];
    }
    __syncthreads();

    // ---- main loop: variance term over own chunk ----
    const float4* sm4 = reinterpret_cast<const float4*>(smf);
    const int n0 = ch * POINTS;
    const float* __restrict__ xb = x + (size_t)b * FF * NN;
    const int*   __restrict__ tb = tgt + (size_t)b * NN;

    float acc = 0.f;
#pragma unroll
    for (int it = 0; it < 2; ++it) {
        const int n = n0 + tid * 4 + it * 1024;
        const int4 t4 = *reinterpret_cast<const int4*>(tb + n);
        const float4 A0 = sm4[3 * t4.x], B0 = sm4[3 * t4.x + 1];
        const float4 A1 = sm4[3 * t4.y], B1 = sm4[3 * t4.y + 1];
        const float4 A2 = sm4[3 * t4.z], B2 = sm4[3 * t4.z + 1];
        const float4 A3 = sm4[3 * t4.w], B3 = sm4[3 * t4.w + 1];
        float s0, s1, s2, s3;
        {
            const float4 v = *reinterpret_cast<const float4*>(xb + 0 * NN + n);
            s0 = fabsf(v.x - A0.x); s1 = fabsf(v.y - A1.x);
            s2 = fabsf(v.z - A2.x); s3 = fabsf(v.w - A3.x);
        }
        {
            const float4 v = *reinterpret_cast<const float4*>(xb + 1 * NN + n);
            s0 += fabsf(v.x - A0.y); s1 += fabsf(v.y - A1.y);
            s2 += fabsf(v.z - A2.y); s3 += fabsf(v.w - A3.y);
        }
        {
            const float4 v = *reinterpret_cast<const float4*>(xb + 2 * NN + n);
            s0 += fabsf(v.x - A0.z); s1 += fabsf(v.y - A1.z);
            s2 += fabsf(v.z - A2.z); s3 += fabsf(v.w - A3.z);
        }
        {
            const float4 v = *reinterpret_cast<const float4*>(xb + 3 * NN + n);
            s0 += fabsf(v.x - A0.w); s1 += fabsf(v.y - A1.w);
            s2 += fabsf(v.z - A2.w); s3 += fabsf(v.w - A3.w);
        }
        {
            const float4 v = *reinterpret_cast<const float4*>(xb + 4 * NN + n);
            s0 += fabsf(v.x - B0.x); s1 += fabsf(v.y - B1.x);
            s2 += fabsf(v.z - B2.x); s3 += fabsf(v.w - B3.x);
        }
        {
            const float4 v = *reinterpret_cast<const float4*>(xb + 5 * NN + n);
            s0 += fabsf(v.x - B0.y); s1 += fabsf(v.y - B1.y);
            s2 += fabsf(v.z - B2.y); s3 += fabsf(v.w - B3.y);
        }
        {
            const float4 v = *reinterpret_cast<const float4*>(xb + 6 * NN + n);
            s0 += fabsf(v.x - B0.z); s1 += fabsf(v.y - B1.z);
            s2 += fabsf(v.z - B2.z); s3 += fabsf(v.w - B3.z);
        }
        {
            const float4 v = *reinterpret_cast<const float4*>(xb + 7 * NN + n);
            s0 += fabsf(v.x - B0.w); s1 += fabsf(v.y - B1.w);
            s2 += fabsf(v.z - B2.w); s3 += fabsf(v.w - B3.w);
        }
        float h;
        h = fmaxf(s0 - DELTA_VAR, 0.f); acc += h * h * sinv[t4.x];
        h = fmaxf(s1 - DELTA_VAR, 0.f); acc += h * h * sinv[t4.y];
        h = fmaxf(s2 - DELTA_VAR, 0.f); acc += h * h * sinv[t4.z];
        h = fmaxf(s3 - DELTA_VAR, 0.f); acc += h * h * sinv[t4.w];
    }

#pragma unroll
    for (int off = 32; off > 0; off >>= 1) acc += __shfl_down(acc, off, 64);
    if ((tid & 63) == 0) wsum[tid >> 6] = acc;
    __syncthreads();

    // ---- dist + reg (ch==0 only; after main loop -> no hot-loop pressure) --
    float contrib = 0.f;
    if (ch == 0 && tid < CC) {
        const int c = tid;
        int labs[CC];                       // 16 ints = one 64B line, L1-hot
#pragma unroll
        for (int j = 0; j < CC; ++j) labs[j] = tb[j];
        float l1 = 0.f;
#pragma unroll
        for (int f = 0; f < FF; ++f) l1 += fabsf(smf[c * 12 + f]);
        const int ti = labs[c];
        float mi[FF];
#pragma unroll
        for (int f = 0; f < FF; ++f) mi[f] = smf[ti * 12 + f];
        float dsum = 0.f;
        for (int j = 0; j < CC; ++j) {
            const int tj = labs[j];
            float d = 0.f;
#pragma unroll
            for (int f = 0; f < FF; ++f) d += fabsf(mi[f] - smf[tj * 12 + f]);
            if (j != c) {
                const float h = 2.f * DELTA_DIST - d;
                if (h > 0.f) dsum += h * h;
            }
        }
        contrib = (GAMMA / (float)(CC * BB)) * l1
                + (BETA / (float)(CC * (CC - 1) * BB)) * dsum;
    }
    if (ch == 0) {
#pragma unroll
        for (int off = 8; off > 0; off >>= 1) contrib += __shfl_down(contrib, off, 64);
    }

    // ---- fire-and-forget epilogue: no returning atomics, no block stalls ---
    if (tid == 0) {
        atomicAdd(&ws[WS_VARB + b], wsum[0] + wsum[1] + wsum[2] + wsum[3]);
        if (ch == 0) atomicAdd(&ws[WS_DRG + b], contrib);
        asm volatile("s_waitcnt vmcnt(0)" ::: "memory");   // data before count
        atomicAdd(&wsi[WS_CNTI], 1);                       // result ignored
    }

    // ---- single spin-finisher: last-dispatched block only -----------------
    if (b == BB - 1 && ch == CHUNKS - 1) {
        if (tid == 0) {
            while (atomicAdd(&wsi[WS_CNTI], 0) < NBLK)
                __builtin_amdgcn_s_sleep(8);
        }
        __syncthreads();
        float val = 0.f;
        if (tid < BB) {
            const float v = atomicAdd(&ws[WS_VARB + tid], 0.f);  // coherent read
            const float d = atomicAdd(&ws[WS_DRG + tid], 0.f);
            val = (ALPHA / (float)BB) * v + d;
        }
#pragma unroll
        for (int off = 16; off > 0; off >>= 1) val += __shfl_down(val, off, 64);
        if (tid == 0) out[0] = val;
    }
}

extern "C" void kernel_launch(void* const* d_in, const int* in_sizes, int n_in,
                              void* d_out, int out_size, void* d_ws, size_t ws_size,
                              hipStream_t stream) {
    const float* x  = (const float*)d_in[0];
    const int* tgt  = (const int*)d_in[1];
    float* out = (float*)d_out;
    float* ws  = (float*)d_ws;
    int*   wsi = (int*)d_ws;

    dim3 grid(CHUNKS, BB);
    k_sums<<<grid, 256, 0, stream>>>(x, tgt, ws, wsi);
    k_var <<<grid, 256, 0, stream>>>(x, tgt, ws, wsi, out);
}

// Round 10
// 57.899 us; speedup vs baseline: 1.1908x; 1.1802x over previous
//
#include <hip/hip_runtime.h>

#define BB 32
#define FF 8
#define NN 131072
#define CC 16

#define CHUNKS 64
#define POINTS (NN / CHUNKS)   // 2048
#define NBLK   (CHUNKS * BB)   // 2048

constexpr float DELTA_VAR  = 0.5f;
constexpr float DELTA_DIST = 1.5f;
constexpr float ALPHA = 1.0f, BETA = 1.0f, GAMMA = 0.001f;

// ws float layout — every slot is written before it is read each launch;
// no zeroing, no atomics anywhere in the pipeline.
#define PSLOT    160                       // 144 used, padded
#define WS_PART  0                         // NBLK*PSLOT
#define WS_VARP  (NBLK * PSLOT)            // NBLK var partials (plain stores)
#define WS_DRG   (WS_VARP + NBLK)          // 32 per-batch dist+reg (plain stores)

// ---------------- Pass 1: per-chunk sums + counts (R6-proven verbatim) ------
__global__ __launch_bounds__(256) void k_sums(const float* __restrict__ x,
                                              const int* __restrict__ tgt,
                                              float* __restrict__ ws) {
    __shared__ float priv[256 * 17];   // 17.4 KB private rows, stride 17
    __shared__ float cpriv[32 * 17];   //  2.2 KB counts (f==0 group)
    const int tid = threadIdx.x;
#pragma unroll
    for (int i = 0; i < 16; ++i) priv[tid * 17 + i] = 0.f;
    if (tid < 32) {
#pragma unroll
        for (int i = 0; i < 16; ++i) cpriv[tid * 17 + i] = 0.f;
    }
    __syncthreads();

    const int b  = blockIdx.y;
    const int ch = blockIdx.x;
    const int f  = tid >> 5;          // feature group 0..7
    const int g  = tid & 31;          // lane-in-group
    const int n0 = ch * POINTS;
    const float* __restrict__ xf = x + (size_t)b * FF * NN + (size_t)f * NN;
    const int*   __restrict__ tb = tgt + (size_t)b * NN;
    const int base  = tid * 17;
    const int cbase = g * 17;

#pragma unroll 2
    for (int k = 0; k < POINTS / 128; ++k) {
        const int n = n0 + k * 128 + g * 4;
        const int4   t4 = *reinterpret_cast<const int4*>(tb + n);
        const float4 v  = *reinterpret_cast<const float4*>(xf + n);
        priv[base + t4.x] += v.x;
        priv[base + t4.y] += v.y;
        priv[base + t4.z] += v.z;
        priv[base + t4.w] += v.w;
        if (f == 0) {
            cpriv[cbase + t4.x] += 1.f;
            cpriv[cbase + t4.y] += 1.f;
            cpriv[cbase + t4.z] += 1.f;
            cpriv[cbase + t4.w] += 1.f;
        }
    }
    __syncthreads();

    // block reduce -> per-block partial slots (plain stores, no atomics)
    float* const part = &ws[WS_PART + (size_t)(b * CHUNKS + ch) * PSLOT];
    if (tid < 128) {
        const int rf = tid >> 4, rc = tid & 15;   // slot = f*16 + c
        float s = 0.f;
#pragma unroll
        for (int gg = 0; gg < 32; ++gg) s += priv[(rf * 32 + gg) * 17 + rc];
        part[tid] = s;
    } else if (tid < 144) {
        const int rc = tid - 128;
        float s = 0.f;
#pragma unroll
        for (int gg = 0; gg < 32; ++gg) s += cpriv[gg * 17 + rc];
        part[tid] = s;
    }
}

// ---------------- Pass 2: variance term; ch==0 also dist+reg (own data) -----
__global__ __launch_bounds__(256) void k_var(const float* __restrict__ x,
                                             const int* __restrict__ tgt,
                                             float* __restrict__ ws) {
    __shared__ float sred[144];
    __shared__ float smf[CC * 12];     // float4-pair rows at stride 3 float4s
    __shared__ float sinv[CC];
    __shared__ float wsum[4];
    __shared__ int   sst[CC];

    const int tid = threadIdx.x;
    const int b   = blockIdx.y;
    const int ch  = blockIdx.x;

    // ---- prologue: derive means/inv from the 64 chunk partials ----
    if (tid < 144) {
        const float* p = &ws[WS_PART + (size_t)b * CHUNKS * PSLOT + tid];
        float s = 0.f;
#pragma unroll 16
        for (int c2 = 0; c2 < CHUNKS; ++c2) s += p[(size_t)c2 * PSLOT];
        sred[tid] = s;
    }
    if (ch == 0 && tid >= 144 && tid < 160) sst[tid - 144] = tgt[(size_t)b * NN + (tid - 144)];
    __syncthreads();
    if (tid < CC) {
        const float cnt = sred[128 + tid];
        sinv[tid] = cnt > 0.f ? 1.f / cnt : 0.f;
    }
    __syncthreads();
    if (tid < 128) {
        const int f = tid >> 4, c = tid & 15;
        smf[c * 12 + f] = sred[tid] * sinv[c];
    }
    __syncthreads();

    // ---- main loop: variance term over own chunk (R6-proven) ----
    const float4* sm4 = reinterpret_cast<const float4*>(smf);
    const int n0 = ch * POINTS;
    const float* __restrict__ xb = x + (size_t)b * FF * NN;
    const int*   __restrict__ tb = tgt + (size_t)b * NN;

    float acc = 0.f;
#pragma unroll
    for (int it = 0; it < 2; ++it) {
        const int n = n0 + tid * 4 + it * 1024;
        const int4 t4 = *reinterpret_cast<const int4*>(tb + n);
        const float4 A0 = sm4[3 * t4.x], B0 = sm4[3 * t4.x + 1];
        const float4 A1 = sm4[3 * t4.y], B1 = sm4[3 * t4.y + 1];
        const float4 A2 = sm4[3 * t4.z], B2 = sm4[3 * t4.z + 1];
        const float4 A3 = sm4[3 * t4.w], B3 = sm4[3 * t4.w + 1];
        float s0, s1, s2, s3;
        {
            const float4 v = *reinterpret_cast<const float4*>(xb + 0 * NN + n);
            s0 = fabsf(v.x - A0.x); s1 = fabsf(v.y - A1.x);
            s2 = fabsf(v.z - A2.x); s3 = fabsf(v.w - A3.x);
        }
        {
            const float4 v = *reinterpret_cast<const float4*>(xb + 1 * NN + n);
            s0 += fabsf(v.x - A0.y); s1 += fabsf(v.y - A1.y);
            s2 += fabsf(v.z - A2.y); s3 += fabsf(v.w - A3.y);
        }
        {
            const float4 v = *reinterpret_cast<const float4*>(xb + 2 * NN + n);
            s0 += fabsf(v.x - A0.z); s1 += fabsf(v.y - A1.z);
            s2 += fabsf(v.z - A2.z); s3 += fabsf(v.w - A3.z);
        }
        {
            const float4 v = *reinterpret_cast<const float4*>(xb + 3 * NN + n);
            s0 += fabsf(v.x - A0.w); s1 += fabsf(v.y - A1.w);
            s2 += fabsf(v.z - A2.w); s3 += fabsf(v.w - A3.w);
        }
        {
            const float4 v = *reinterpret_cast<const float4*>(xb + 4 * NN + n);
            s0 += fabsf(v.x - B0.x); s1 += fabsf(v.y - B1.x);
            s2 += fabsf(v.z - B2.x); s3 += fabsf(v.w - B3.x);
        }
        {
            const float4 v = *reinterpret_cast<const float4*>(xb + 5 * NN + n);
            s0 += fabsf(v.x - B0.y); s1 += fabsf(v.y - B1.y);
            s2 += fabsf(v.z - B2.y); s3 += fabsf(v.w - B3.y);
        }
        {
            const float4 v = *reinterpret_cast<const float4*>(xb + 6 * NN + n);
            s0 += fabsf(v.x - B0.z); s1 += fabsf(v.y - B1.z);
            s2 += fabsf(v.z - B2.z); s3 += fabsf(v.w - B3.z);
        }
        {
            const float4 v = *reinterpret_cast<const float4*>(xb + 7 * NN + n);
            s0 += fabsf(v.x - B0.w); s1 += fabsf(v.y - B1.w);
            s2 += fabsf(v.z - B2.w); s3 += fabsf(v.w - B3.w);
        }
        float h;
        h = fmaxf(s0 - DELTA_VAR, 0.f); acc += h * h * sinv[t4.x];
        h = fmaxf(s1 - DELTA_VAR, 0.f); acc += h * h * sinv[t4.y];
        h = fmaxf(s2 - DELTA_VAR, 0.f); acc += h * h * sinv[t4.z];
        h = fmaxf(s3 - DELTA_VAR, 0.f); acc += h * h * sinv[t4.w];
    }

#pragma unroll
    for (int off = 32; off > 0; off >>= 1) acc += __shfl_down(acc, off, 64);
    if ((tid & 63) == 0) wsum[tid >> 6] = acc;
    __syncthreads();
    if (tid == 0) ws[WS_VARP + b * CHUNKS + ch] = wsum[0] + wsum[1] + wsum[2] + wsum[3];

    // ---- ch==0 only: dist + reg from OWN means (plain store, no sync) ----
    if (ch == 0 && tid < CC) {
        const int c = tid;
        float l1 = 0.f;
#pragma unroll
        for (int f = 0; f < FF; ++f) l1 += fabsf(smf[c * 12 + f]);
        const int ti = sst[c];
        float mi[FF];
#pragma unroll
        for (int f = 0; f < FF; ++f) mi[f] = smf[ti * 12 + f];
        float dsum = 0.f;
        for (int j = 0; j < CC; ++j) {
            const int tj = sst[j];
            float d = 0.f;
#pragma unroll
            for (int f = 0; f < FF; ++f) d += fabsf(mi[f] - smf[tj * 12 + f]);
            if (j != c) {
                const float h = 2.f * DELTA_DIST - d;
                if (h > 0.f) dsum += h * h;
            }
        }
        float contrib = (GAMMA / (float)(CC * BB)) * l1
                      + (BETA / (float)(CC * (CC - 1) * BB)) * dsum;
#pragma unroll
        for (int off = 8; off > 0; off >>= 1) contrib += __shfl_down(contrib, off, 64);
        if (tid == 0) ws[WS_DRG + b] = contrib;
    }
}

// ---------------- Final: pure reduce of 2048 var partials + 32 drg ----------
__global__ __launch_bounds__(256) void k_final(const float* __restrict__ ws,
                                               float* __restrict__ out) {
    __shared__ float red[4];
    const int tid = threadIdx.x;

    float v = 0.f;
#pragma unroll
    for (int i = 0; i < NBLK / 256; ++i) v += ws[WS_VARP + i * 256 + tid];
    float val = (ALPHA / (float)BB) * v;
    if (tid < BB) val += ws[WS_DRG + tid];

#pragma unroll
    for (int off = 32; off > 0; off >>= 1) val += __shfl_down(val, off, 64);
    if ((tid & 63) == 0) red[tid >> 6] = val;
    __syncthreads();
    if (tid == 0) out[0] = red[0] + red[1] + red[2] + red[3];
}

extern "C" void kernel_launch(void* const* d_in, const int* in_sizes, int n_in,
                              void* d_out, int out_size, void* d_ws, size_t ws_size,
                              hipStream_t stream) {
    const float* x  = (const float*)d_in[0];
    const int* tgt  = (const int*)d_in[1];
    float* out = (float*)d_out;
    float* ws  = (float*)d_ws;

    dim3 grid(CHUNKS, BB);
    k_sums<<<grid, 256, 0, stream>>>(x, tgt, ws);
    k_var <<<grid, 256, 0, stream>>>(x, tgt, ws);
    k_final<<<1, 256, 0, stream>>>(ws, out);
}